// Round 14
// baseline (136.572 us; speedup 1.0000x reference)
//
#include <hip/hip_runtime.h>
#include <math.h>

typedef _Float16 f16;
typedef _Float16 f16x2 __attribute__((ext_vector_type(2)));
typedef _Float16 f16x4 __attribute__((ext_vector_type(4)));
typedef _Float16 f16x8 __attribute__((ext_vector_type(8)));
typedef float f32x4 __attribute__((ext_vector_type(4)));

#define EPS_ 1e-5f

// ws element counts (halves unless noted)
#define N_XP   3551232   // x_pad [8][34][34][384] (zero borders)
#define N_WDCN 1327104   // wdcn_p [54][384][64]
#define N_WOFF 331776    // woff_p [54][96][64]
#define N_W2   147456    // w2_p [6][384][64]
#define N_OFFS 589824    // offs (f32) [8192][72]
#define N_YH   3145728   // y [8192][384]
#define N_AS   28311552  // A_t [128 tiles][54 ck][64 row][64 c] (big-ws path only)

#define WS_NEED ((size_t)(N_XP + N_WDCN + N_WOFF + N_W2 + N_AS + N_YH) * 2 + (size_t)N_OFFS * 4)

static __device__ __forceinline__ f16x8 sp8(f16 h) { return (f16x8){h,h,h,h,h,h,h,h}; }

#define GLD_LDS16(g, l) __builtin_amdgcn_global_load_lds( \
    (const __attribute__((address_space(1))) void*)(g),   \
    (__attribute__((address_space(3))) void*)(l), 16, 0, 0)

#define VMCNT(N) asm volatile("s_waitcnt vmcnt(" #N ")" ::: "memory")

// ---------------- pack: x->f16 padded xp, weights -> [ck][oc][kc] f16 ----------------
#define PK_X   786432    // f16x4 groups of x -> xp interior
#define PK_XP  101376    // f16x4 groups of xp border zero-fill
#define PK_WD  147456
#define PK_WO  27648
#define PK_WZ  10368
#define PK_W2  147456
__global__ void k_pack(const float* __restrict__ x, const float* __restrict__ w_off,
                       const float* __restrict__ w_dcn, const float* __restrict__ w2,
                       f16* __restrict__ xp, f16* __restrict__ woffp,
                       f16* __restrict__ wdcnp, f16* __restrict__ w2p) {
    long i = (long)blockIdx.x * 256 + threadIdx.x;
    if (i < PK_X) {                          // x: float4 -> f16x4 into xp interior
        float4 v = ((const float4*)x)[i];
        f16x4 hv; hv.x = (f16)v.x; hv.y = (f16)v.y; hv.z = (f16)v.z; hv.w = (f16)v.w;
        int m = (int)(i / 96), c4 = (int)(i % 96);
        int b = m >> 10, h = (m >> 5) & 31, w = m & 31;
        long idx = ((long)(b * 34 + h + 1) * 34 + (w + 1)) * 96 + c4;
        ((f16x4*)xp)[idx] = hv;
    } else if (i < PK_X + PK_XP) {           // xp border zero-fill
        int j = (int)(i - PK_X);
        int cell = j / 96, c4 = j % 96;
        int b = cell / 132, p = cell % 132;
        int r, cp;
        if (p < 34)       { r = 0;          cp = p; }
        else if (p < 68)  { r = 33;         cp = p - 34; }
        else if (p < 100) { r = p - 68 + 1; cp = 0; }
        else              { r = p - 100 + 1; cp = 33; }
        long idx = ((long)(b * 34 + r) * 34 + cp) * 96 + c4;
        ((f16x4*)xp)[idx] = (f16x4){};
    } else if (i < PK_X + PK_XP + PK_WD) {   // w_dcn: thread = (oc,c), 9 kk each
        int j = (int)(i - PK_X - PK_XP);
        int c = j % 384, oc = j / 384;
#pragma unroll
        for (int kk = 0; kk < 9; ++kk) {
            f16 v = (f16)w_dcn[(long)j * 9 + kk];
            wdcnp[(long)(kk * 6 + (c >> 6)) * 24576 + oc * 64 + (c & 63)] = v;
        }
    } else if (i < PK_X + PK_XP + PK_WD + PK_WO) {   // w_off
        int j = (int)(i - PK_X - PK_XP - PK_WD);
        int c = j % 384, oc = j / 384;
#pragma unroll
        for (int kk = 0; kk < 9; ++kk) {
            f16 v = (f16)w_off[(long)j * 9 + kk];
            woffp[(long)(kk * 6 + (c >> 6)) * 6144 + oc * 64 + (c & 63)] = v;
        }
    } else if (i < PK_X + PK_XP + PK_WD + PK_WO + PK_WZ) {  // woffp oc>=72 zero fill
        int j = (int)(i - PK_X - PK_XP - PK_WD - PK_WO);
        int ck = j / 192, r = j % 192;
        *(f16x8*)(&woffp[(long)ck * 6144 + 72 * 64 + r * 8]) = (f16x8){};
    } else if (i < PK_X + PK_XP + PK_WD + PK_WO + PK_WZ + PK_W2) {  // w2
        long j = i - (PK_X + PK_XP + PK_WD + PK_WO + PK_WZ);
        int kc = (int)(j & 63); long r = j >> 6;
        int oc = (int)(r % 384); int cc = (int)(r / 384);
        w2p[j] = (f16)w2[(long)oc * 384 + cc * 64 + kc];
    }
}

// ---------------- stage A: offset conv — 4-deep 1-barrier split-K pipeline (unchanged) ----------------
__global__ __launch_bounds__(256, 2) void k_off_gemm4(
        const f16* __restrict__ xp, const f16* __restrict__ wp,
        float* __restrict__ part) {
    __shared__ __attribute__((aligned(16))) f16 As[4][64 * 64];
    __shared__ __attribute__((aligned(16))) f16 Bs[4][96 * 64];
    int t = threadIdx.x;
    int bx = blockIdx.x;
    int ks = blockIdx.y;
    bx = (bx & 7) * 16 + (bx >> 3);        // XCD j <- image j
    int m0 = bx * 64;
    int w = t >> 6, l = t & 63, lr = l & 15, lq = l >> 4;
    int wmi = w & 1, wni = w >> 1;
    f32x4 acc[2][3] = {};

    const f16* a_base[2];
#pragma unroll
    for (int i = 0; i < 2; ++i) {
        int f = i * 256 + t;
        int ml = f >> 3, c8 = f & 7;
        int m = m0 + ml;
        int b = m >> 10, h = (m >> 5) & 31, ww = m & 31;
        a_base[i] = xp + ((long)(b * 34 + h + 1) * 34 + (ww + 1)) * 384 + ((c8 ^ (ml & 7)) * 8);
    }
    const f16* b_src[3];
#pragma unroll
    for (int i = 0; i < 3; ++i) {
        int f = i * 256 + t;
        int oc = f >> 3, c8 = f & 7;
        b_src[i] = wp + (long)oc * 64 + ((c8 ^ (oc & 7)) * 8);
    }

    int s_ck = (54 * ks) >> 2, e_ck = (54 * (ks + 1)) >> 2;
    int nck = e_ck - s_ck;

    auto stage = [&](int j, int buf) {
        int ck = s_ck + j;
        int kk = ck / 6, cc = ck % 6;
        int kkd = ((kk / 3 - 1) * 34 + (kk % 3 - 1)) * 384 + cc * 64;
#pragma unroll
        for (int i = 0; i < 2; ++i)
            GLD_LDS16(a_base[i] + kkd, &As[buf][i * 2048 + w * 512]);
#pragma unroll
        for (int i = 0; i < 3; ++i)
            GLD_LDS16(b_src[i] + (long)ck * 6144, &Bs[buf][i * 2048 + w * 512]);
    };
    auto compute = [&](int buf) {
        const char* Ab = (const char*)&As[buf][0];
        const char* Bb = (const char*)&Bs[buf][0];
        __builtin_amdgcn_s_setprio(1);
#pragma unroll
        for (int s = 0; s < 2; ++s) {
            int j = (s << 2) | lq;
            int swz = (j ^ (lr & 7)) * 16;
            f16x8 af[2], bf[3];
#pragma unroll
            for (int mi = 0; mi < 2; ++mi)
                af[mi] = *(const f16x8*)(Ab + (wmi * 32 + mi * 16 + lr) * 128 + swz);
#pragma unroll
            for (int n = 0; n < 3; ++n)
                bf[n] = *(const f16x8*)(Bb + (wni * 48 + n * 16 + lr) * 128 + swz);
#pragma unroll
            for (int mi = 0; mi < 2; ++mi)
#pragma unroll
                for (int n = 0; n < 3; ++n)
                    acc[mi][n] = __builtin_amdgcn_mfma_f32_16x16x32_f16(af[mi], bf[n], acc[mi][n], 0, 0, 0);
        }
        __builtin_amdgcn_s_setprio(0);
    };

    stage(0, 0);
    stage(1, 1);
    for (int j = 0; j < nck; ++j) {
        if (j + 2 < nck) {
            stage(j + 2, (j + 2) & 3);
            VMCNT(10);
        } else if (j + 1 < nck) {
            VMCNT(5);
        } else {
            VMCNT(0);
        }
        __builtin_amdgcn_s_barrier();      // single barrier: 4-deep rotation is race-free
        compute(j & 3);
    }
    float* pb = part + (long)ks * (96 * 8192);
#pragma unroll
    for (int n = 0; n < 3; ++n) {
        int oc = wni * 48 + 16 * n + lr;
#pragma unroll
        for (int mi = 0; mi < 2; ++mi) {
            int m = m0 + wmi * 32 + 16 * mi + 4 * lq;
            *(f32x4*)(&pb[(long)oc * 8192 + m]) = acc[mi][n];
        }
    }
}

// reduce 4 K-split partials (transposed layout) + bias -> offs[m][72]
__global__ __launch_bounds__(256) void k_off_reduce(
        const float* __restrict__ part, const float* __restrict__ b_off,
        float* __restrict__ offs) {
    int j = blockIdx.x * 256 + threadIdx.x;   // 72*2048 = 147456
    int oc = j >> 11;
    int mq = (j & 2047) << 2;
    const long S = 96L * 8192;
    f32x4 s0 = *(const f32x4*)(&part[(long)oc * 8192 + mq]);
    f32x4 s1 = *(const f32x4*)(&part[S + (long)oc * 8192 + mq]);
    f32x4 s2 = *(const f32x4*)(&part[2 * S + (long)oc * 8192 + mq]);
    f32x4 s3 = *(const f32x4*)(&part[3 * S + (long)oc * 8192 + mq]);
    f32x4 s = s0 + s1 + s2 + s3;
    float b = b_off[oc];
#pragma unroll
    for (int r = 0; r < 4; ++r)
        offs[(long)(mq + r) * 72 + oc] = s[r] + b;
}

// ---------------- stage B1: sampler v2 — coalesced A_t writes, LDS-shared coords ----------------
__global__ __launch_bounds__(256) void k_sample(
        const f16* __restrict__ xp, const float* __restrict__ offs,
        f16* __restrict__ A_t) {
    __shared__ int   cad[64][4][4];
    __shared__ f16x4 cwd[64][4];
    int t = threadIdx.x;
    int raw = blockIdx.x;
    int bx = (raw & 7) * 16 + (raw >> 3);   // XCD i <- image i
    int kk = blockIdx.y;
    int m0 = bx * 64;
    {   // phase 1
        int row = t & 63, g = t >> 6;
        int m = m0 + row;
        int b = m >> 10, h = (m >> 5) & 31, wpix = m & 31;
        const float2 o = *(const float2*)(offs + (long)m * 72 + (g * 9 + kk) * 2);
        float py = o.x + (float)(h + kk / 3 - 1);
        float px = o.y + (float)(wpix + kk % 3 - 1);
        float fy = floorf(py), fx = floorf(px);
        int iy0 = (int)fy, ix0 = (int)fx;
        float wy1 = py - fy, wx1 = px - fx;
        float wy0 = 1.f - wy1, wx0 = 1.f - wx1;
        bool vy0 = iy0 >= 0 && iy0 < 32, vy1 = iy0 + 1 >= 0 && iy0 + 1 < 32;
        bool vx0 = ix0 >= 0 && ix0 < 32, vx1 = ix0 + 1 >= 0 && ix0 + 1 < 32;
        int cy0 = min(max(iy0, 0), 31), cy1 = min(max(iy0 + 1, 0), 31);
        int cx0 = min(max(ix0, 0), 31), cx1 = min(max(ix0 + 1, 0), 31);
        cad[row][g][0] = ((b * 34 + cy0 + 1) * 34 + cx0 + 1) * 768;
        cad[row][g][1] = ((b * 34 + cy0 + 1) * 34 + cx1 + 1) * 768;
        cad[row][g][2] = ((b * 34 + cy1 + 1) * 34 + cx0 + 1) * 768;
        cad[row][g][3] = ((b * 34 + cy1 + 1) * 34 + cx1 + 1) * 768;
        f16x4 wv;
        wv.x = (f16)(wy0 * wx0 * ((vy0 && vx0) ? 1.f : 0.f));
        wv.y = (f16)(wy0 * wx1 * ((vy0 && vx1) ? 1.f : 0.f));
        wv.z = (f16)(wy1 * wx0 * ((vy1 && vx0) ? 1.f : 0.f));
        wv.w = (f16)(wy1 * wx1 * ((vy1 && vx1) ? 1.f : 0.f));
        cwd[row][g] = wv;
    }
    __syncthreads();
    int rb = t >> 3, w8 = t & 7;
    const char* xb = (const char*)xp;
    long obase = ((long)bx * 54 + (long)kk * 6) * 4096;
#pragma unroll
    for (int cc = 0; cc < 6; ++cc) {
        int c = cc * 64 + 8 * w8;
        int g = c / 96;
        long cb = (long)c * 2;
#pragma unroll
        for (int rr = 0; rr < 2; ++rr) {
            int r = 2 * rb + rr;
            const int* ca = cad[r][g];
            f16x4 wv = cwd[r][g];
            f16x8 v0 = *(const f16x8*)(xb + ca[0] + cb);
            f16x8 v1 = *(const f16x8*)(xb + ca[1] + cb);
            f16x8 v2 = *(const f16x8*)(xb + ca[2] + cb);
            f16x8 v3 = *(const f16x8*)(xb + ca[3] + cb);
            f16x8 ov = v0 * sp8(wv.x) + v1 * sp8(wv.y) + v2 * sp8(wv.z) + v3 * sp8(wv.w);
            *(f16x8*)(A_t + obase + cc * 4096 + r * 64 + ((w8 ^ (r & 7)) * 8)) = ov;
        }
    }
}

// ---------------- stage B2: dense GEMM — A via 4-deep LDS (32KB), B direct-to-register ----------------
// dbuf, 1 barrier/chunk, counted vmcnt(8). 3 blocks/CU.
__global__ __launch_bounds__(256, 3) void k_dcn_gemm2(
        const f16* __restrict__ A_t, const f16* __restrict__ Bp,
        const float* __restrict__ bng, const float* __restrict__ bnb,
        const float* __restrict__ bnm, const float* __restrict__ bnv,
        f16* __restrict__ yh) {
    __shared__ __attribute__((aligned(16))) f16 As[4][64 * 64];
    int t = threadIdx.x;
    int bx = blockIdx.x;
    bx = (bx & 7) * 16 + (bx >> 3);        // XCD i <- image i
    int m0 = bx * 64;
    int n0 = blockIdx.y * 96;
    int w = t >> 6, l = t & 63, lr = l & 15, lq = l >> 4;
    int wmi = w & 1, wni = w >> 1;          // wave tile 32M x 48N
    f32x4 acc[2][3] = {};

    const f16* a_base = A_t + (long)bx * 54 * 4096 + t * 8;
    const f16* b_frag = Bp + (long)(n0 + wni * 48 + lr) * 64 + 8 * lq;

    auto stageA = [&](int ck, int buf) {
#pragma unroll
        for (int i = 0; i < 2; ++i)
            GLD_LDS16(a_base + (long)ck * 4096 + i * 2048, &As[buf][i * 2048 + w * 512]);
    };
    auto ldB = [&](f16x8 bf[3][2], int ck) {
        const f16* wb = b_frag + (long)ck * 24576;
#pragma unroll
        for (int n = 0; n < 3; ++n)
#pragma unroll
            for (int s = 0; s < 2; ++s)
                bf[n][s] = *(const f16x8*)(wb + n * 16 * 64 + 32 * s);
    };
    auto compute = [&](int buf, f16x8 bf[3][2]) {
        const char* Ab = (const char*)&As[buf][0];
        __builtin_amdgcn_s_setprio(1);
#pragma unroll
        for (int s = 0; s < 2; ++s) {
            int j = (s << 2) | lq;
            int swz = (j ^ (lr & 7)) * 16;
            f16x8 af[2];
#pragma unroll
            for (int mi = 0; mi < 2; ++mi)
                af[mi] = *(const f16x8*)(Ab + (wmi * 32 + mi * 16 + lr) * 128 + swz);
#pragma unroll
            for (int mi = 0; mi < 2; ++mi)
#pragma unroll
                for (int n = 0; n < 3; ++n)
                    acc[mi][n] = __builtin_amdgcn_mfma_f32_16x16x32_f16(af[mi], bf[n][s], acc[mi][n], 0, 0, 0);
        }
        __builtin_amdgcn_s_setprio(0);
    };

    f16x8 b0[3][2], b1[3][2];
    stageA(0, 0);
    stageA(1, 1);
    ldB(b0, 0);
    for (int c2 = 0; c2 < 27; ++c2) {
        int ck = 2 * c2;
        // even chunk ck (uses b0)
        if (ck + 2 < 54) stageA(ck + 2, (ck + 2) & 3);
        ldB(b1, ck + 1);
        VMCNT(8);                          // A(ck) landed; A(ck+2)+B(ck+1) stay in flight
        __builtin_amdgcn_s_barrier();
        compute(ck & 3, b0);
        // odd chunk ck+1 (uses b1)
        if (ck + 3 < 54) stageA(ck + 3, (ck + 3) & 3);
        if (ck + 2 < 54) { ldB(b0, ck + 2); VMCNT(8); }
        else             { VMCNT(0); }
        __builtin_amdgcn_s_barrier();
        compute((ck + 1) & 3, b1);
    }
#pragma unroll
    for (int n = 0; n < 3; ++n) {
        int oc = n0 + wni * 48 + n * 16 + lr;
        float sc = bng[oc] * rsqrtf(bnv[oc] + EPS_);
        float shf = bnb[oc] - bnm[oc] * sc;
#pragma unroll
        for (int mi = 0; mi < 2; ++mi)
#pragma unroll
            for (int r = 0; r < 4; ++r) {
                int m = m0 + wmi * 32 + mi * 16 + 4 * lq + r;
                float v = acc[mi][n][r] * sc + shf;
                v = v / (1.f + __expf(-v));
                yh[(long)m * 384 + oc] = (f16)v;
            }
    }
}

// ---------------- fallback fused DCN (small ws) — reads padded xp ----------------
__global__ __launch_bounds__(512, 2) void k_dcn_fused(
        const f16* __restrict__ xp, const float* __restrict__ offs,
        const f16* __restrict__ wp,
        const float* __restrict__ bng, const float* __restrict__ bnb,
        const float* __restrict__ bnm, const float* __restrict__ bnv,
        f16* __restrict__ yh) {
    __shared__ __attribute__((aligned(16))) f16 As[2][64 * 72];
    __shared__ __attribute__((aligned(16))) int ca[2][4][64][4];
    __shared__ __attribute__((aligned(16))) f16x4 cwl[2][4][64];
    int t = threadIdx.x;
    int bx = blockIdx.x;
    bx = (bx & 7) * 16 + (bx >> 3);
    int m0 = bx * 64;
    int n0 = blockIdx.y * 192;
    int w = t >> 6, l = t & 63, lr = l & 15, lq = l >> 4;
    int wm = (w & 1) * 32, wn = (w >> 1) * 48;
    int spx = t >> 3, slot = t & 7;
    const char* xb = (const char*)xp;
    f32x4 acc[2][3] = {};

    auto coords = [&](int kkn, int bufn) {
        if (t < 256) {
            int g = t >> 6, px = t & 63;
            int m = m0 + px;
            int b = m >> 10, h = (m >> 5) & 31, wwp = m & 31;
            int ky = kkn / 3 - 1, kx = kkn % 3 - 1;
            const float2 o = *(const float2*)(offs + (long)m * 72 + (g * 9 + kkn) * 2);
            float py = o.x + (float)(h + ky);
            float pxx = o.y + (float)(wwp + kx);
            float fy = floorf(py), fx = floorf(pxx);
            int iy0 = (int)fy, ix0 = (int)fx;
            float wy1 = py - fy, wx1 = pxx - fx;
            float wy0 = 1.f - wy1, wx0 = 1.f - wx1;
            bool vy0 = iy0 >= 0 && iy0 < 32, vy1 = iy0 + 1 >= 0 && iy0 + 1 < 32;
            bool vx0 = ix0 >= 0 && ix0 < 32, vx1 = ix0 + 1 >= 0 && ix0 + 1 < 32;
            int cy0 = min(max(iy0, 0), 31), cy1 = min(max(iy0 + 1, 0), 31);
            int cx0 = min(max(ix0, 0), 31), cx1 = min(max(ix0 + 1, 0), 31);
            ca[bufn][g][px][0] = ((b * 34 + cy0 + 1) * 34 + cx0 + 1) * 768;
            ca[bufn][g][px][1] = ((b * 34 + cy0 + 1) * 34 + cx1 + 1) * 768;
            ca[bufn][g][px][2] = ((b * 34 + cy1 + 1) * 34 + cx0 + 1) * 768;
            ca[bufn][g][px][3] = ((b * 34 + cy1 + 1) * 34 + cx1 + 1) * 768;
            f16x4 wv;
            wv.x = (f16)(wy0 * wx0 * ((vy0 && vx0) ? 1.f : 0.f));
            wv.y = (f16)(wy0 * wx1 * ((vy0 && vx1) ? 1.f : 0.f));
            wv.z = (f16)(wy1 * wx0 * ((vy1 && vx0) ? 1.f : 0.f));
            wv.w = (f16)(wy1 * wx1 * ((vy1 && vx1) ? 1.f : 0.f));
            cwl[bufn][g][px] = wv;
        }
    };

    coords(0, 0);
    __syncthreads();
    {
        int cst = 8 * slot;
        int g = cst / 96;
        int4 cv = *(const int4*)(&ca[0][g][spx][0]);
        f16x4 wv = cwl[0][g][spx];
        long cb = (long)(cst * 2);
        f16x8 v0 = *(const f16x8*)(xb + cv.x + cb);
        f16x8 v1 = *(const f16x8*)(xb + cv.y + cb);
        f16x8 v2 = *(const f16x8*)(xb + cv.z + cb);
        f16x8 v3 = *(const f16x8*)(xb + cv.w + cb);
        f16x8 sv = v0 * sp8(wv.x) + v1 * sp8(wv.y) + v2 * sp8(wv.z) + v3 * sp8(wv.w);
        *(f16x8*)(&As[0][spx * 72 + 8 * slot]) = sv;
    }
    int cur = 0, kk = 0, cc = 0;
    for (int ck = 0; ck < 54; ++ck) {
        __syncthreads();
        bool hn = ck < 53;
        int kk2 = kk + (cc == 5), cc2 = (cc == 5) ? 0 : (cc + 1);
        f16x8 v0, v1, v2, v3; f16x4 wv;
        if (hn) {
            int cst = cc2 * 64 + 8 * slot;
            int g = cst / 96;
            int kb = kk2 & 1;
            int4 cv = *(const int4*)(&ca[kb][g][spx][0]);
            wv = cwl[kb][g][spx];
            long cb = (long)(cst * 2);
            v0 = *(const f16x8*)(xb + cv.x + cb);
            v1 = *(const f16x8*)(xb + cv.y + cb);
            v2 = *(const f16x8*)(xb + cv.z + cb);
            v3 = *(const f16x8*)(xb + cv.w + cb);
        }
        if (cc == 4 && kk < 8) coords(kk + 1, (kk + 1) & 1);
        const f16* wbase = wp + (long)ck * (384 * 64);
#pragma unroll
        for (int s = 0; s < 2; ++s) {
            f16x8 a0 = *(const f16x8*)(&As[cur][(wm + lr) * 72 + 32 * s + 8 * lq]);
            f16x8 a1 = *(const f16x8*)(&As[cur][(wm + 16 + lr) * 72 + 32 * s + 8 * lq]);
#pragma unroll
            for (int n = 0; n < 3; ++n) {
                f16x8 b = *(const f16x8*)(wbase + (long)(n0 + wn + 16 * n + lr) * 64 + 32 * s + 8 * lq);
                acc[0][n] = __builtin_amdgcn_mfma_f32_16x16x32_f16(a0, b, acc[0][n], 0, 0, 0);
                acc[1][n] = __builtin_amdgcn_mfma_f32_16x16x32_f16(a1, b, acc[1][n], 0, 0, 0);
            }
        }
        if (hn) {
            f16x8 sv = v0 * sp8(wv.x) + v1 * sp8(wv.y) + v2 * sp8(wv.z) + v3 * sp8(wv.w);
            *(f16x8*)(&As[cur ^ 1][spx * 72 + 8 * slot]) = sv;
        }
        cur ^= 1; kk = kk2; cc = cc2;
    }
#pragma unroll
    for (int n = 0; n < 3; ++n) {
        int oc = n0 + wn + 16 * n + lr;
        float sc = bng[oc] * rsqrtf(bnv[oc] + EPS_);
        float sh = bnb[oc] - bnm[oc] * sc;
#pragma unroll
        for (int mi = 0; mi < 2; ++mi)
#pragma unroll
            for (int r = 0; r < 4; ++r) {
                int m = m0 + wm + 16 * mi + 4 * lq + r;
                float v = acc[mi][n][r] * sc + sh;
                v = v / (1.f + __expf(-v));
                yh[(long)m * 384 + oc] = (f16)v;
            }
    }
}

// ---------------- stage C: 1x1 projection — A via LDS, B direct-to-register ----------------
__global__ __launch_bounds__(256, 3) void k_out_gemm3(
        const f16* __restrict__ yh, const f16* __restrict__ wp,
        const float* __restrict__ b2, float* __restrict__ out) {
    __shared__ __attribute__((aligned(16))) f16 As[4][64 * 64];
    int t = threadIdx.x;
    int bx = blockIdx.x;
    bx = (bx & 7) * 16 + (bx >> 3);        // XCD i <- image i
    int m0 = bx * 64;
    int n0 = blockIdx.y * 96;
    int w = t >> 6, l = t & 63, lr = l & 15, lq = l >> 4;
    int wmi = w & 1, wni = w >> 1;
    f32x4 acc[2][3] = {};

    const f16* a_src[2];
#pragma unroll
    for (int i = 0; i < 2; ++i) {
        int f = i * 256 + t;
        int ml = f >> 3, c8 = f & 7;
        a_src[i] = yh + (long)(m0 + ml) * 384 + ((c8 ^ (ml & 7)) * 8);
    }
    const f16* b_frag = wp + (long)(n0 + wni * 48 + lr) * 64 + 8 * lq;

    auto stageA = [&](int cc, int buf) {
#pragma unroll
        for (int i = 0; i < 2; ++i)
            GLD_LDS16(a_src[i] + cc * 64, &As[buf][i * 2048 + w * 512]);
    };
    auto ldB = [&](f16x8 bf[3][2], int cc) {
        const f16* wb = b_frag + (long)cc * 24576;
#pragma unroll
        for (int n = 0; n < 3; ++n)
#pragma unroll
            for (int s = 0; s < 2; ++s)
                bf[n][s] = *(const f16x8*)(wb + n * 16 * 64 + 32 * s);
    };
    auto compute = [&](int buf, f16x8 bf[3][2]) {
        const char* Ab = (const char*)&As[buf][0];
        __builtin_amdgcn_s_setprio(1);
#pragma unroll
        for (int s = 0; s < 2; ++s) {
            int j = (s << 2) | lq;
            int swz = (j ^ (lr & 7)) * 16;
            f16x8 af[2];
#pragma unroll
            for (int mi = 0; mi < 2; ++mi)
                af[mi] = *(const f16x8*)(Ab + (wmi * 32 + mi * 16 + lr) * 128 + swz);
#pragma unroll
            for (int mi = 0; mi < 2; ++mi)
#pragma unroll
                for (int n = 0; n < 3; ++n)
                    acc[mi][n] = __builtin_amdgcn_mfma_f32_16x16x32_f16(af[mi], bf[n][s], acc[mi][n], 0, 0, 0);
        }
        __builtin_amdgcn_s_setprio(0);
    };

    f16x8 b0[3][2], b1[3][2];
    stageA(0, 0);
    stageA(1, 1);
    ldB(b0, 0);
    for (int c2 = 0; c2 < 3; ++c2) {
        int cc = 2 * c2;
        if (cc + 2 < 6) stageA(cc + 2, (cc + 2) & 3);
        ldB(b1, cc + 1);
        VMCNT(8);
        __builtin_amdgcn_s_barrier();
        compute(cc & 3, b0);
        if (cc + 3 < 6) stageA(cc + 3, (cc + 3) & 3);
        if (cc + 2 < 6) { ldB(b0, cc + 2); VMCNT(8); }
        else            { VMCNT(0); }
        __builtin_amdgcn_s_barrier();
        compute((cc + 1) & 3, b1);
    }
#pragma unroll
    for (int n = 0; n < 3; ++n) {
        int oc = n0 + wni * 48 + 16 * n + lr;
        float bia = b2[oc];
#pragma unroll
        for (int mi = 0; mi < 2; ++mi)
#pragma unroll
            for (int r = 0; r < 4; ++r) {
                int m = m0 + wmi * 32 + 16 * mi + 4 * lq + r;
                out[(long)m * 384 + oc] = acc[mi][n][r] + bia;
            }
    }
}

extern "C" void kernel_launch(void* const* d_in, const int* in_sizes, int n_in,
                              void* d_out, int out_size, void* d_ws, size_t ws_size,
                              hipStream_t stream) {
    const float* x        = (const float*)d_in[0];
    const float* w_off    = (const float*)d_in[1];
    const float* b_off    = (const float*)d_in[2];
    const float* w_dcn    = (const float*)d_in[3];
    const float* bn_gamma = (const float*)d_in[4];
    const float* bn_beta  = (const float*)d_in[5];
    const float* bn_mean  = (const float*)d_in[6];
    const float* bn_var   = (const float*)d_in[7];
    const float* w2       = (const float*)d_in[8];
    const float* b2       = (const float*)d_in[9];

    char* ws = (char*)d_ws;
    f16*   xp    = (f16*)ws;                                  ws += (size_t)N_XP * 2;
    f16*   wdcnp = (f16*)ws;                                  ws += (size_t)N_WDCN * 2;
    f16*   woffp = (f16*)ws;                                  ws += (size_t)N_WOFF * 2;
    f16*   w2p   = (f16*)ws;                                  ws += (size_t)N_W2 * 2;
    float* offs  = (float*)ws;                                ws += (size_t)N_OFFS * 4;
    f16*   yh    = (f16*)ws;                                  ws += (size_t)N_YH * 2;
    f16*   A_t   = (f16*)ws;                                  // big-ws path only
    bool big = ws_size >= WS_NEED;
    float* part = (float*)(big ? (void*)A_t : (void*)ws);

    k_pack<<<4770, 256, 0, stream>>>(x, w_off, w_dcn, w2, xp, woffp, wdcnp, w2p);
    k_off_gemm4<<<dim3(128, 4), 256, 0, stream>>>(xp, woffp, part);
    k_off_reduce<<<576, 256, 0, stream>>>(part, b_off, offs);

    if (big) {
        k_sample<<<dim3(128, 9), 256, 0, stream>>>(xp, offs, A_t);
        k_dcn_gemm2<<<dim3(128, 4), 256, 0, stream>>>(A_t, wdcnp,
                bn_gamma, bn_beta, bn_mean, bn_var, yh);
    } else {
        k_dcn_fused<<<dim3(128, 2), 512, 0, stream>>>(xp, offs, wdcnp,
                bn_gamma, bn_beta, bn_mean, bn_var, yh);
    }
    k_out_gemm3<<<dim3(128, 4), 256, 0, stream>>>(yh, w2p, b2, (float*)d_out);
}

// Round 15
// 84.056 us; speedup vs baseline: 1.6248x; 1.6248x over previous
//
#include <hip/hip_runtime.h>
#include <math.h>

typedef _Float16 f16;
typedef _Float16 f16x2 __attribute__((ext_vector_type(2)));
typedef _Float16 f16x4 __attribute__((ext_vector_type(4)));
typedef _Float16 f16x8 __attribute__((ext_vector_type(8)));
typedef float f32x4 __attribute__((ext_vector_type(4)));

#define EPS_ 1e-5f

// ws element counts (halves unless noted)
#define N_XP   3551232   // x_pad [8][34][34][384] (zero borders)
#define N_WDCN 1327104   // wdcn_p [54][384][64]
#define N_WOFF 331776    // woff_p [54][96][64]
#define N_W2   147456    // w2_p [6][384][64]
#define N_OFFS 589824    // offs (f32) [8192][72]
#define N_YH   3145728   // y [8192][384]
#define N_AS   28311552  // A_t [128 tiles][54 ck][64 row][64 c] (big-ws path only)

#define WS_NEED ((size_t)(N_XP + N_WDCN + N_WOFF + N_W2 + N_AS + N_YH) * 2 + (size_t)N_OFFS * 4)

static __device__ __forceinline__ f16x8 sp8(f16 h) { return (f16x8){h,h,h,h,h,h,h,h}; }

#define GLD_LDS16(g, l) __builtin_amdgcn_global_load_lds( \
    (const __attribute__((address_space(1))) void*)(g),   \
    (__attribute__((address_space(3))) void*)(l), 16, 0, 0)

#define VMCNT(N) asm volatile("s_waitcnt vmcnt(" #N ")" ::: "memory")

// ---------------- pack: x->f16 padded xp, weights -> [ck][oc][kc] f16 ----------------
#define PK_X   786432    // f16x4 groups of x -> xp interior
#define PK_XP  101376    // f16x4 groups of xp border zero-fill
#define PK_WD  147456
#define PK_WO  27648
#define PK_WZ  10368
#define PK_W2  147456
__global__ void k_pack(const float* __restrict__ x, const float* __restrict__ w_off,
                       const float* __restrict__ w_dcn, const float* __restrict__ w2,
                       f16* __restrict__ xp, f16* __restrict__ woffp,
                       f16* __restrict__ wdcnp, f16* __restrict__ w2p) {
    long i = (long)blockIdx.x * 256 + threadIdx.x;
    if (i < PK_X) {                          // x: float4 -> f16x4 into xp interior
        float4 v = ((const float4*)x)[i];
        f16x4 hv; hv.x = (f16)v.x; hv.y = (f16)v.y; hv.z = (f16)v.z; hv.w = (f16)v.w;
        int m = (int)(i / 96), c4 = (int)(i % 96);
        int b = m >> 10, h = (m >> 5) & 31, w = m & 31;
        long idx = ((long)(b * 34 + h + 1) * 34 + (w + 1)) * 96 + c4;
        ((f16x4*)xp)[idx] = hv;
    } else if (i < PK_X + PK_XP) {           // xp border zero-fill
        int j = (int)(i - PK_X);
        int cell = j / 96, c4 = j % 96;
        int b = cell / 132, p = cell % 132;
        int r, cp;
        if (p < 34)       { r = 0;          cp = p; }
        else if (p < 68)  { r = 33;         cp = p - 34; }
        else if (p < 100) { r = p - 68 + 1; cp = 0; }
        else              { r = p - 100 + 1; cp = 33; }
        long idx = ((long)(b * 34 + r) * 34 + cp) * 96 + c4;
        ((f16x4*)xp)[idx] = (f16x4){};
    } else if (i < PK_X + PK_XP + PK_WD) {   // w_dcn: thread = (oc,c), 9 kk each
        int j = (int)(i - PK_X - PK_XP);
        int c = j % 384, oc = j / 384;
#pragma unroll
        for (int kk = 0; kk < 9; ++kk) {
            f16 v = (f16)w_dcn[(long)j * 9 + kk];
            wdcnp[(long)(kk * 6 + (c >> 6)) * 24576 + oc * 64 + (c & 63)] = v;
        }
    } else if (i < PK_X + PK_XP + PK_WD + PK_WO) {   // w_off
        int j = (int)(i - PK_X - PK_XP - PK_WD);
        int c = j % 384, oc = j / 384;
#pragma unroll
        for (int kk = 0; kk < 9; ++kk) {
            f16 v = (f16)w_off[(long)j * 9 + kk];
            woffp[(long)(kk * 6 + (c >> 6)) * 6144 + oc * 64 + (c & 63)] = v;
        }
    } else if (i < PK_X + PK_XP + PK_WD + PK_WO + PK_WZ) {  // woffp oc>=72 zero fill
        int j = (int)(i - PK_X - PK_XP - PK_WD - PK_WO);
        int ck = j / 192, r = j % 192;
        *(f16x8*)(&woffp[(long)ck * 6144 + 72 * 64 + r * 8]) = (f16x8){};
    } else if (i < PK_X + PK_XP + PK_WD + PK_WO + PK_WZ + PK_W2) {  // w2
        long j = i - (PK_X + PK_XP + PK_WD + PK_WO + PK_WZ);
        int kc = (int)(j & 63); long r = j >> 6;
        int oc = (int)(r % 384); int cc = (int)(r / 384);
        w2p[j] = (f16)w2[(long)oc * 384 + cc * 64 + kc];
    }
}

// ---------------- stage A: offset conv — 4-deep 1-barrier split-K pipeline ----------------
__global__ __launch_bounds__(256, 2) void k_off_gemm4(
        const f16* __restrict__ xp, const f16* __restrict__ wp,
        float* __restrict__ part) {
    __shared__ __attribute__((aligned(16))) f16 As[4][64 * 64];
    __shared__ __attribute__((aligned(16))) f16 Bs[4][96 * 64];
    int t = threadIdx.x;
    int bx = blockIdx.x;
    int ks = blockIdx.y;
    bx = (bx & 7) * 16 + (bx >> 3);        // XCD j <- image j
    int m0 = bx * 64;
    int w = t >> 6, l = t & 63, lr = l & 15, lq = l >> 4;
    int wmi = w & 1, wni = w >> 1;
    f32x4 acc[2][3] = {};

    const f16* a_base[2];
#pragma unroll
    for (int i = 0; i < 2; ++i) {
        int f = i * 256 + t;
        int ml = f >> 3, c8 = f & 7;
        int m = m0 + ml;
        int b = m >> 10, h = (m >> 5) & 31, ww = m & 31;
        a_base[i] = xp + ((long)(b * 34 + h + 1) * 34 + (ww + 1)) * 384 + ((c8 ^ (ml & 7)) * 8);
    }
    const f16* b_src[3];
#pragma unroll
    for (int i = 0; i < 3; ++i) {
        int f = i * 256 + t;
        int oc = f >> 3, c8 = f & 7;
        b_src[i] = wp + (long)oc * 64 + ((c8 ^ (oc & 7)) * 8);
    }

    int s_ck = (54 * ks) >> 2, e_ck = (54 * (ks + 1)) >> 2;
    int nck = e_ck - s_ck;

    auto stage = [&](int j, int buf) {
        int ck = s_ck + j;
        int kk = ck / 6, cc = ck % 6;
        int kkd = ((kk / 3 - 1) * 34 + (kk % 3 - 1)) * 384 + cc * 64;
#pragma unroll
        for (int i = 0; i < 2; ++i)
            GLD_LDS16(a_base[i] + kkd, &As[buf][i * 2048 + w * 512]);
#pragma unroll
        for (int i = 0; i < 3; ++i)
            GLD_LDS16(b_src[i] + (long)ck * 6144, &Bs[buf][i * 2048 + w * 512]);
    };
    auto compute = [&](int buf) {
        const char* Ab = (const char*)&As[buf][0];
        const char* Bb = (const char*)&Bs[buf][0];
        __builtin_amdgcn_s_setprio(1);
#pragma unroll
        for (int s = 0; s < 2; ++s) {
            int j = (s << 2) | lq;
            int swz = (j ^ (lr & 7)) * 16;
            f16x8 af[2], bf[3];
#pragma unroll
            for (int mi = 0; mi < 2; ++mi)
                af[mi] = *(const f16x8*)(Ab + (wmi * 32 + mi * 16 + lr) * 128 + swz);
#pragma unroll
            for (int n = 0; n < 3; ++n)
                bf[n] = *(const f16x8*)(Bb + (wni * 48 + n * 16 + lr) * 128 + swz);
#pragma unroll
            for (int mi = 0; mi < 2; ++mi)
#pragma unroll
                for (int n = 0; n < 3; ++n)
                    acc[mi][n] = __builtin_amdgcn_mfma_f32_16x16x32_f16(af[mi], bf[n], acc[mi][n], 0, 0, 0);
        }
        __builtin_amdgcn_s_setprio(0);
    };

    stage(0, 0);
    stage(1, 1);
    for (int j = 0; j < nck; ++j) {
        if (j + 2 < nck) {
            stage(j + 2, (j + 2) & 3);
            VMCNT(10);
        } else if (j + 1 < nck) {
            VMCNT(5);
        } else {
            VMCNT(0);
        }
        __builtin_amdgcn_s_barrier();      // single barrier: 4-deep rotation is race-free
        compute(j & 3);
    }
    float* pb = part + (long)ks * (96 * 8192);
#pragma unroll
    for (int n = 0; n < 3; ++n) {
        int oc = wni * 48 + 16 * n + lr;
#pragma unroll
        for (int mi = 0; mi < 2; ++mi) {
            int m = m0 + wmi * 32 + 16 * mi + 4 * lq;
            *(f32x4*)(&pb[(long)oc * 8192 + m]) = acc[mi][n];
        }
    }
}

// reduce 4 K-split partials (transposed layout) + bias -> offs[m][72]
__global__ __launch_bounds__(256) void k_off_reduce(
        const float* __restrict__ part, const float* __restrict__ b_off,
        float* __restrict__ offs) {
    int j = blockIdx.x * 256 + threadIdx.x;   // 72*2048 = 147456
    int oc = j >> 11;
    int mq = (j & 2047) << 2;
    const long S = 96L * 8192;
    f32x4 s0 = *(const f32x4*)(&part[(long)oc * 8192 + mq]);
    f32x4 s1 = *(const f32x4*)(&part[S + (long)oc * 8192 + mq]);
    f32x4 s2 = *(const f32x4*)(&part[2 * S + (long)oc * 8192 + mq]);
    f32x4 s3 = *(const f32x4*)(&part[3 * S + (long)oc * 8192 + mq]);
    f32x4 s = s0 + s1 + s2 + s3;
    float b = b_off[oc];
#pragma unroll
    for (int r = 0; r < 4; ++r)
        offs[(long)(mq + r) * 72 + oc] = s[r] + b;
}

// ---------------- stage B1: sampler v2 — coalesced A_t writes, LDS-shared coords ----------------
__global__ __launch_bounds__(256) void k_sample(
        const f16* __restrict__ xp, const float* __restrict__ offs,
        f16* __restrict__ A_t) {
    __shared__ int   cad[64][4][4];
    __shared__ f16x4 cwd[64][4];
    int t = threadIdx.x;
    int raw = blockIdx.x;
    int bx = (raw & 7) * 16 + (raw >> 3);   // XCD i <- image i
    int kk = blockIdx.y;
    int m0 = bx * 64;
    {   // phase 1
        int row = t & 63, g = t >> 6;
        int m = m0 + row;
        int b = m >> 10, h = (m >> 5) & 31, wpix = m & 31;
        const float2 o = *(const float2*)(offs + (long)m * 72 + (g * 9 + kk) * 2);
        float py = o.x + (float)(h + kk / 3 - 1);
        float px = o.y + (float)(wpix + kk % 3 - 1);
        float fy = floorf(py), fx = floorf(px);
        int iy0 = (int)fy, ix0 = (int)fx;
        float wy1 = py - fy, wx1 = px - fx;
        float wy0 = 1.f - wy1, wx0 = 1.f - wx1;
        bool vy0 = iy0 >= 0 && iy0 < 32, vy1 = iy0 + 1 >= 0 && iy0 + 1 < 32;
        bool vx0 = ix0 >= 0 && ix0 < 32, vx1 = ix0 + 1 >= 0 && ix0 + 1 < 32;
        int cy0 = min(max(iy0, 0), 31), cy1 = min(max(iy0 + 1, 0), 31);
        int cx0 = min(max(ix0, 0), 31), cx1 = min(max(ix0 + 1, 0), 31);
        cad[row][g][0] = ((b * 34 + cy0 + 1) * 34 + cx0 + 1) * 768;
        cad[row][g][1] = ((b * 34 + cy0 + 1) * 34 + cx1 + 1) * 768;
        cad[row][g][2] = ((b * 34 + cy1 + 1) * 34 + cx0 + 1) * 768;
        cad[row][g][3] = ((b * 34 + cy1 + 1) * 34 + cx1 + 1) * 768;
        f16x4 wv;
        wv.x = (f16)(wy0 * wx0 * ((vy0 && vx0) ? 1.f : 0.f));
        wv.y = (f16)(wy0 * wx1 * ((vy0 && vx1) ? 1.f : 0.f));
        wv.z = (f16)(wy1 * wx0 * ((vy1 && vx0) ? 1.f : 0.f));
        wv.w = (f16)(wy1 * wx1 * ((vy1 && vx1) ? 1.f : 0.f));
        cwd[row][g] = wv;
    }
    __syncthreads();
    int rb = t >> 3, w8 = t & 7;
    const char* xb = (const char*)xp;
    long obase = ((long)bx * 54 + (long)kk * 6) * 4096;
#pragma unroll
    for (int cc = 0; cc < 6; ++cc) {
        int c = cc * 64 + 8 * w8;
        int g = c / 96;
        long cb = (long)c * 2;
#pragma unroll
        for (int rr = 0; rr < 2; ++rr) {
            int r = 2 * rb + rr;
            const int* ca = cad[r][g];
            f16x4 wv = cwd[r][g];
            f16x8 v0 = *(const f16x8*)(xb + ca[0] + cb);
            f16x8 v1 = *(const f16x8*)(xb + ca[1] + cb);
            f16x8 v2 = *(const f16x8*)(xb + ca[2] + cb);
            f16x8 v3 = *(const f16x8*)(xb + ca[3] + cb);
            f16x8 ov = v0 * sp8(wv.x) + v1 * sp8(wv.y) + v2 * sp8(wv.z) + v3 * sp8(wv.w);
            *(f16x8*)(A_t + obase + cc * 4096 + r * 64 + ((w8 ^ (r & 7)) * 8)) = ov;
        }
    }
}

// ---------------- stage B2: dense GEMM M=8192 N=384 K=3456 + BN + SiLU ----------------
// 4-deep LDS (80KB), ONE barrier per chunk, counted vmcnt.
__global__ __launch_bounds__(256, 2) void k_dcn_gemm2(
        const f16* __restrict__ A_t, const f16* __restrict__ Bp,
        const float* __restrict__ bng, const float* __restrict__ bnb,
        const float* __restrict__ bnm, const float* __restrict__ bnv,
        f16* __restrict__ yh) {
    __shared__ __attribute__((aligned(16))) f16 As[4][64 * 64];
    __shared__ __attribute__((aligned(16))) f16 Bs[4][96 * 64];
    int t = threadIdx.x;
    int bx = blockIdx.x;
    bx = (bx & 7) * 16 + (bx >> 3);        // XCD i <- image i
    int m0 = bx * 64;
    int n0 = blockIdx.y * 96;
    int w = t >> 6, l = t & 63, lr = l & 15, lq = l >> 4;
    int wmi = w & 1, wni = w >> 1;          // wave tile 32M x 48N
    f32x4 acc[2][3] = {};

    const f16* a_base = A_t + (long)bx * 54 * 4096 + t * 8;
    const f16* b_src[3];
#pragma unroll
    for (int i = 0; i < 3; ++i) {
        int f = i * 256 + t;
        int oc = f >> 3, c8 = f & 7;
        b_src[i] = Bp + (long)(n0 + oc) * 64 + ((c8 ^ (oc & 7)) * 8);
    }

    auto stage = [&](int ck, int buf) {
#pragma unroll
        for (int i = 0; i < 2; ++i)
            GLD_LDS16(a_base + (long)ck * 4096 + i * 2048, &As[buf][i * 2048 + w * 512]);
#pragma unroll
        for (int i = 0; i < 3; ++i)
            GLD_LDS16(b_src[i] + (long)ck * 24576, &Bs[buf][i * 2048 + w * 512]);
    };
    auto compute = [&](int buf) {
        const char* Ab = (const char*)&As[buf][0];
        const char* Bb = (const char*)&Bs[buf][0];
        __builtin_amdgcn_s_setprio(1);
#pragma unroll
        for (int s = 0; s < 2; ++s) {
            int j = (s << 2) | lq;
            int swz = (j ^ (lr & 7)) * 16;
            f16x8 af[2], bf[3];
#pragma unroll
            for (int mi = 0; mi < 2; ++mi)
                af[mi] = *(const f16x8*)(Ab + (wmi * 32 + mi * 16 + lr) * 128 + swz);
#pragma unroll
            for (int n = 0; n < 3; ++n)
                bf[n] = *(const f16x8*)(Bb + (wni * 48 + n * 16 + lr) * 128 + swz);
#pragma unroll
            for (int mi = 0; mi < 2; ++mi)
#pragma unroll
                for (int n = 0; n < 3; ++n)
                    acc[mi][n] = __builtin_amdgcn_mfma_f32_16x16x32_f16(af[mi], bf[n], acc[mi][n], 0, 0, 0);
        }
        __builtin_amdgcn_s_setprio(0);
    };

    stage(0, 0);
    stage(1, 1);
    for (int ck = 0; ck < 54; ++ck) {
        if (ck + 2 < 54) {
            stage(ck + 2, (ck + 2) & 3);
            VMCNT(10);
        } else if (ck + 1 < 54) {
            VMCNT(5);
        } else {
            VMCNT(0);
        }
        __builtin_amdgcn_s_barrier();      // single barrier (4-deep rotation)
        compute(ck & 3);
    }
#pragma unroll
    for (int n = 0; n < 3; ++n) {
        int oc = n0 + wni * 48 + n * 16 + lr;
        float sc = bng[oc] * rsqrtf(bnv[oc] + EPS_);
        float shf = bnb[oc] - bnm[oc] * sc;
#pragma unroll
        for (int mi = 0; mi < 2; ++mi)
#pragma unroll
            for (int r = 0; r < 4; ++r) {
                int m = m0 + wmi * 32 + mi * 16 + 4 * lq + r;
                float v = acc[mi][n][r] * sc + shf;
                v = v / (1.f + __expf(-v));
                yh[(long)m * 384 + oc] = (f16)v;
            }
    }
}

// ---------------- fallback fused DCN (small ws) — reads padded xp ----------------
__global__ __launch_bounds__(512, 2) void k_dcn_fused(
        const f16* __restrict__ xp, const float* __restrict__ offs,
        const f16* __restrict__ wp,
        const float* __restrict__ bng, const float* __restrict__ bnb,
        const float* __restrict__ bnm, const float* __restrict__ bnv,
        f16* __restrict__ yh) {
    __shared__ __attribute__((aligned(16))) f16 As[2][64 * 72];
    __shared__ __attribute__((aligned(16))) int ca[2][4][64][4];
    __shared__ __attribute__((aligned(16))) f16x4 cwl[2][4][64];
    int t = threadIdx.x;
    int bx = blockIdx.x;
    bx = (bx & 7) * 16 + (bx >> 3);
    int m0 = bx * 64;
    int n0 = blockIdx.y * 192;
    int w = t >> 6, l = t & 63, lr = l & 15, lq = l >> 4;
    int wm = (w & 1) * 32, wn = (w >> 1) * 48;
    int spx = t >> 3, slot = t & 7;
    const char* xb = (const char*)xp;
    f32x4 acc[2][3] = {};

    auto coords = [&](int kkn, int bufn) {
        if (t < 256) {
            int g = t >> 6, px = t & 63;
            int m = m0 + px;
            int b = m >> 10, h = (m >> 5) & 31, wwp = m & 31;
            int ky = kkn / 3 - 1, kx = kkn % 3 - 1;
            const float2 o = *(const float2*)(offs + (long)m * 72 + (g * 9 + kkn) * 2);
            float py = o.x + (float)(h + ky);
            float pxx = o.y + (float)(wwp + kx);
            float fy = floorf(py), fx = floorf(pxx);
            int iy0 = (int)fy, ix0 = (int)fx;
            float wy1 = py - fy, wx1 = pxx - fx;
            float wy0 = 1.f - wy1, wx0 = 1.f - wx1;
            bool vy0 = iy0 >= 0 && iy0 < 32, vy1 = iy0 + 1 >= 0 && iy0 + 1 < 32;
            bool vx0 = ix0 >= 0 && ix0 < 32, vx1 = ix0 + 1 >= 0 && ix0 + 1 < 32;
            int cy0 = min(max(iy0, 0), 31), cy1 = min(max(iy0 + 1, 0), 31);
            int cx0 = min(max(ix0, 0), 31), cx1 = min(max(ix0 + 1, 0), 31);
            ca[bufn][g][px][0] = ((b * 34 + cy0 + 1) * 34 + cx0 + 1) * 768;
            ca[bufn][g][px][1] = ((b * 34 + cy0 + 1) * 34 + cx1 + 1) * 768;
            ca[bufn][g][px][2] = ((b * 34 + cy1 + 1) * 34 + cx0 + 1) * 768;
            ca[bufn][g][px][3] = ((b * 34 + cy1 + 1) * 34 + cx1 + 1) * 768;
            f16x4 wv;
            wv.x = (f16)(wy0 * wx0 * ((vy0 && vx0) ? 1.f : 0.f));
            wv.y = (f16)(wy0 * wx1 * ((vy0 && vx1) ? 1.f : 0.f));
            wv.z = (f16)(wy1 * wx0 * ((vy1 && vx0) ? 1.f : 0.f));
            wv.w = (f16)(wy1 * wx1 * ((vy1 && vx1) ? 1.f : 0.f));
            cwl[bufn][g][px] = wv;
        }
    };

    coords(0, 0);
    __syncthreads();
    {
        int cst = 8 * slot;
        int g = cst / 96;
        int4 cv = *(const int4*)(&ca[0][g][spx][0]);
        f16x4 wv = cwl[0][g][spx];
        long cb = (long)(cst * 2);
        f16x8 v0 = *(const f16x8*)(xb + cv.x + cb);
        f16x8 v1 = *(const f16x8*)(xb + cv.y + cb);
        f16x8 v2 = *(const f16x8*)(xb + cv.z + cb);
        f16x8 v3 = *(const f16x8*)(xb + cv.w + cb);
        f16x8 sv = v0 * sp8(wv.x) + v1 * sp8(wv.y) + v2 * sp8(wv.z) + v3 * sp8(wv.w);
        *(f16x8*)(&As[0][spx * 72 + 8 * slot]) = sv;
    }
    int cur = 0, kk = 0, cc = 0;
    for (int ck = 0; ck < 54; ++ck) {
        __syncthreads();
        bool hn = ck < 53;
        int kk2 = kk + (cc == 5), cc2 = (cc == 5) ? 0 : (cc + 1);
        f16x8 v0, v1, v2, v3; f16x4 wv;
        if (hn) {
            int cst = cc2 * 64 + 8 * slot;
            int g = cst / 96;
            int kb = kk2 & 1;
            int4 cv = *(const int4*)(&ca[kb][g][spx][0]);
            wv = cwl[kb][g][spx];
            long cb = (long)(cst * 2);
            v0 = *(const f16x8*)(xb + cv.x + cb);
            v1 = *(const f16x8*)(xb + cv.y + cb);
            v2 = *(const f16x8*)(xb + cv.z + cb);
            v3 = *(const f16x8*)(xb + cv.w + cb);
        }
        if (cc == 4 && kk < 8) coords(kk + 1, (kk + 1) & 1);
        const f16* wbase = wp + (long)ck * (384 * 64);
#pragma unroll
        for (int s = 0; s < 2; ++s) {
            f16x8 a0 = *(const f16x8*)(&As[cur][(wm + lr) * 72 + 32 * s + 8 * lq]);
            f16x8 a1 = *(const f16x8*)(&As[cur][(wm + 16 + lr) * 72 + 32 * s + 8 * lq]);
#pragma unroll
            for (int n = 0; n < 3; ++n) {
                f16x8 b = *(const f16x8*)(wbase + (long)(n0 + wn + 16 * n + lr) * 64 + 32 * s + 8 * lq);
                acc[0][n] = __builtin_amdgcn_mfma_f32_16x16x32_f16(a0, b, acc[0][n], 0, 0, 0);
                acc[1][n] = __builtin_amdgcn_mfma_f32_16x16x32_f16(a1, b, acc[1][n], 0, 0, 0);
            }
        }
        if (hn) {
            f16x8 sv = v0 * sp8(wv.x) + v1 * sp8(wv.y) + v2 * sp8(wv.z) + v3 * sp8(wv.w);
            *(f16x8*)(&As[cur ^ 1][spx * 72 + 8 * slot]) = sv;
        }
        cur ^= 1; kk = kk2; cc = cc2;
    }
#pragma unroll
    for (int n = 0; n < 3; ++n) {
        int oc = n0 + wn + 16 * n + lr;
        float sc = bng[oc] * rsqrtf(bnv[oc] + EPS_);
        float sh = bnb[oc] - bnm[oc] * sc;
#pragma unroll
        for (int mi = 0; mi < 2; ++mi)
#pragma unroll
            for (int r = 0; r < 4; ++r) {
                int m = m0 + wm + 16 * mi + 4 * lq + r;
                float v = acc[mi][n][r] * sc + sh;
                v = v / (1.f + __expf(-v));
                yh[(long)m * 384 + oc] = (f16)v;
            }
    }
}

// ---------------- stage C: 1x1 projection — 4-deep 1-barrier pipeline ----------------
__global__ __launch_bounds__(256, 2) void k_out_gemm3(
        const f16* __restrict__ yh, const f16* __restrict__ wp,
        const float* __restrict__ b2, float* __restrict__ out) {
    __shared__ __attribute__((aligned(16))) f16 As[4][64 * 64];
    __shared__ __attribute__((aligned(16))) f16 Bs[4][96 * 64];
    int t = threadIdx.x;
    int bx = blockIdx.x;
    bx = (bx & 7) * 16 + (bx >> 3);        // XCD i <- image i
    int m0 = bx * 64;
    int n0 = blockIdx.y * 96;
    int w = t >> 6, l = t & 63, lr = l & 15, lq = l >> 4;
    int wmi = w & 1, wni = w >> 1;
    f32x4 acc[2][3] = {};

    const f16* a_src[2];
#pragma unroll
    for (int i = 0; i < 2; ++i) {
        int f = i * 256 + t;
        int ml = f >> 3, c8 = f & 7;
        a_src[i] = yh + (long)(m0 + ml) * 384 + ((c8 ^ (ml & 7)) * 8);
    }
    const f16* b_src[3];
#pragma unroll
    for (int i = 0; i < 3; ++i) {
        int f = i * 256 + t;
        int oc = f >> 3, c8 = f & 7;
        b_src[i] = wp + (long)(n0 + oc) * 64 + ((c8 ^ (oc & 7)) * 8);
    }

    auto stage = [&](int cc, int buf) {
#pragma unroll
        for (int i = 0; i < 2; ++i)
            GLD_LDS16(a_src[i] + cc * 64, &As[buf][i * 2048 + w * 512]);
#pragma unroll
        for (int i = 0; i < 3; ++i)
            GLD_LDS16(b_src[i] + (long)cc * 24576, &Bs[buf][i * 2048 + w * 512]);
    };
    auto compute = [&](int buf) {
        const char* Ab = (const char*)&As[buf][0];
        const char* Bb = (const char*)&Bs[buf][0];
        __builtin_amdgcn_s_setprio(1);
#pragma unroll
        for (int s = 0; s < 2; ++s) {
            int j = (s << 2) | lq;
            int swz = (j ^ (lr & 7)) * 16;
            f16x8 af[2], bf[3];
#pragma unroll
            for (int mi = 0; mi < 2; ++mi)
                af[mi] = *(const f16x8*)(Ab + (wmi * 32 + mi * 16 + lr) * 128 + swz);
#pragma unroll
            for (int n = 0; n < 3; ++n)
                bf[n] = *(const f16x8*)(Bb + (wni * 48 + n * 16 + lr) * 128 + swz);
#pragma unroll
            for (int mi = 0; mi < 2; ++mi)
#pragma unroll
                for (int n = 0; n < 3; ++n)
                    acc[mi][n] = __builtin_amdgcn_mfma_f32_16x16x32_f16(af[mi], bf[n], acc[mi][n], 0, 0, 0);
        }
        __builtin_amdgcn_s_setprio(0);
    };

    stage(0, 0);
    stage(1, 1);
    for (int cc = 0; cc < 6; ++cc) {
        if (cc + 2 < 6) {
            stage(cc + 2, (cc + 2) & 3);
            VMCNT(10);
        } else if (cc + 1 < 6) {
            VMCNT(5);
        } else {
            VMCNT(0);
        }
        __builtin_amdgcn_s_barrier();
        compute(cc & 3);
    }
#pragma unroll
    for (int n = 0; n < 3; ++n) {
        int oc = n0 + wni * 48 + 16 * n + lr;
        float bia = b2[oc];
#pragma unroll
        for (int mi = 0; mi < 2; ++mi)
#pragma unroll
            for (int r = 0; r < 4; ++r) {
                int m = m0 + wmi * 32 + 16 * mi + 4 * lq + r;
                out[(long)m * 384 + oc] = acc[mi][n][r] + bia;
            }
    }
}

extern "C" void kernel_launch(void* const* d_in, const int* in_sizes, int n_in,
                              void* d_out, int out_size, void* d_ws, size_t ws_size,
                              hipStream_t stream) {
    const float* x        = (const float*)d_in[0];
    const float* w_off    = (const float*)d_in[1];
    const float* b_off    = (const float*)d_in[2];
    const float* w_dcn    = (const float*)d_in[3];
    const float* bn_gamma = (const float*)d_in[4];
    const float* bn_beta  = (const float*)d_in[5];
    const float* bn_mean  = (const float*)d_in[6];
    const float* bn_var   = (const float*)d_in[7];
    const float* w2       = (const float*)d_in[8];
    const float* b2       = (const float*)d_in[9];

    char* ws = (char*)d_ws;
    f16*   xp    = (f16*)ws;                                  ws += (size_t)N_XP * 2;
    f16*   wdcnp = (f16*)ws;                                  ws += (size_t)N_WDCN * 2;
    f16*   woffp = (f16*)ws;                                  ws += (size_t)N_WOFF * 2;
    f16*   w2p   = (f16*)ws;                                  ws += (size_t)N_W2 * 2;
    float* offs  = (float*)ws;                                ws += (size_t)N_OFFS * 4;
    f16*   yh    = (f16*)ws;                                  ws += (size_t)N_YH * 2;
    f16*   A_t   = (f16*)ws;                                  // big-ws path only
    bool big = ws_size >= WS_NEED;
    float* part = (float*)(big ? (void*)A_t : (void*)ws);

    k_pack<<<4770, 256, 0, stream>>>(x, w_off, w_dcn, w2, xp, woffp, wdcnp, w2p);
    k_off_gemm4<<<dim3(128, 4), 256, 0, stream>>>(xp, woffp, part);
    k_off_reduce<<<576, 256, 0, stream>>>(part, b_off, offs);

    if (big) {
        k_sample<<<dim3(128, 9), 256, 0, stream>>>(xp, offs, A_t);
        k_dcn_gemm2<<<dim3(128, 4), 256, 0, stream>>>(A_t, wdcnp,
                bn_gamma, bn_beta, bn_mean, bn_var, yh);
    } else {
        k_dcn_fused<<<dim3(128, 2), 512, 0, stream>>>(xp, offs, wdcnp,
                bn_gamma, bn_beta, bn_mean, bn_var, yh);
    }
    k_out_gemm3<<<dim3(128, 4), 256, 0, stream>>>(yh, w2p, b2, (float*)d_out);
}